// Round 9
// baseline (204.720 us; speedup 1.0000x reference)
//
#include <hip/hip_runtime.h>

// Spatial transformer: trilinear warp of src by flow, border padding.
// D=160, H=192, W=160.  u = (idx + flow) * S/(S-1) - 0.5, clamp, trilinear.
// grid input (identity meshgrid) recomputed from thread index.
//
// R8 lesson: LDS-staged kernel was throttled by the INLINE out-of-window
// fallback -- exec-masked scattered gathers stall the wave ~500cyc in most
// hot-loop iterations. R9: hot loop is pure LDS (clamped indices, OOW mask
// in regs); OOW voxels (~1-3%) are queued in LDS (overlaid on the dead
// window buffer) and batch-processed after -- one parallel round trip.

#define DD 160
#define HH 192
#define WW 160
#define DHW (DD * HH * WW)

#define TZ 8
#define TY 8
#define TX 32
#define WIN_Z 23
#define WIN_Y 23
#define WIN_X 48
#define NTX 5
#define NTY 24
#define NTZ 20
#define NTILES (NTZ * NTY * NTX)             /* 2400 = 8*300 */
#define NCHUNK (WIN_Z * WIN_Y * (WIN_X / 8)) /* 3174 16B-chunks */
#define SROWY WIN_X
#define SROWZ (WIN_Y * WIN_X)
#define SBUF_N (WIN_Z * WIN_Y * WIN_X)       /* 25392 entries */

struct __align__(4) F2 { float a, b; };

__device__ __forceinline__ float bf2f(unsigned int s) {
    return __uint_as_float(s << 16);
}

__global__ __launch_bounds__(256) void warp_tile_kernel(
    const float* __restrict__ src,
    const float* __restrict__ flow,
    float* __restrict__ out)
{
    __shared__ unsigned short sbuf[SBUF_N];   // 50,784 B
    __shared__ int qcount;

    // XCD swizzle: XCD k gets tiles [300k,300k+300) = contiguous z-slab;
    // its src slab (~2.7 MB incl halo) stays resident in that XCD's 4 MiB L2.
    int b = blockIdx.x;
    int nb = (b & 7) * 300 + (b >> 3);
    int tzt = nb / (NTY * NTX);
    int rem = nb - tzt * (NTY * NTX);
    int tyt = rem / NTX;
    int txt = rem - tyt * NTX;
    int bz = tzt * TZ, by = tyt * TY, bx = txt * TX;
    int zlo = bz - 7, ylo = by - 7, xlo = bx - 8;

    int tid = (int)threadIdx.x;
    if (tid == 0) qcount = 0;

    // ---- voxel-group indices: 8 voxels/thread as 2 float4 groups ----
    int row0 = tid >> 3;
    int col  = tid & 7;
    int tz0 = row0 >> 3, ty0 = row0 & 7;
    int gz0 = bz + tz0, gy0 = by + ty0;  // group 1 adds +4 to z
    int gx  = bx + col * 4;
    int idx0 = (gz0 * HH + gy0) * WW + gx;
    int idx1 = idx0 + 4 * HH * WW;

    // ---- flow loads FIRST (in flight during staging; pinned pre-barrier) ----
    float4 f0a = *(const float4*)(flow + idx0);
    float4 f1a = *(const float4*)(flow + DHW + idx0);
    float4 f2a = *(const float4*)(flow + 2 * DHW + idx0);
    float4 f0b = *(const float4*)(flow + idx1);
    float4 f1b = *(const float4*)(flow + DHW + idx1);
    float4 f2b = *(const float4*)(flow + 2 * DHW + idx1);

    // ---- stage window: 3174 chunks of 8 entries (32B fp32 -> 16B bf16) ----
    #pragma unroll
    for (int k = 0; k < 13; ++k) {
        int c = tid + k * 256;
        if (c < NCHUNK) {
            int r = c / 6, i = c - r * 6;
            int wz = r / WIN_Y, wy = r - wz * WIN_Y;
            int gz = min(max(zlo + wz, 0), DD - 1);
            int gy = min(max(ylo + wy, 0), HH - 1);
            const float* rowp = src + (gz * HH + gy) * WW;
            int gx0 = xlo + i * 8;
            float4 a, bb;
            if ((unsigned)gx0 <= (unsigned)(WW - 8)) {
                a  = *(const float4*)(rowp + gx0);
                bb = *(const float4*)(rowp + gx0 + 4);
            } else {
                float v = rowp[gx0 < 0 ? 0 : WW - 1];
                a = make_float4(v, v, v, v); bb = a;
            }
            unsigned a0 = __float_as_uint(a.x) + 0x8000u, a1 = __float_as_uint(a.y) + 0x8000u;
            unsigned a2 = __float_as_uint(a.z) + 0x8000u, a3 = __float_as_uint(a.w) + 0x8000u;
            unsigned b0 = __float_as_uint(bb.x) + 0x8000u, b1 = __float_as_uint(bb.y) + 0x8000u;
            unsigned b2 = __float_as_uint(bb.z) + 0x8000u, b3 = __float_as_uint(bb.w) + 0x8000u;
            uint4 pk;
            pk.x = (a1 & 0xFFFF0000u) | (a0 >> 16);
            pk.y = (a3 & 0xFFFF0000u) | (a2 >> 16);
            pk.z = (b1 & 0xFFFF0000u) | (b0 >> 16);
            pk.w = (b3 & 0xFFFF0000u) | (b2 >> 16);
            *(uint4*)&sbuf[r * WIN_X + i * 8] = pk;
        }
    }

    // Pin flow values pre-barrier: their waitcnt merges with the barrier
    // drain -> post-barrier hot loop has zero global-latency exposure.
    asm volatile("" :
        "+v"(f0a.x), "+v"(f0a.y), "+v"(f0a.z), "+v"(f0a.w),
        "+v"(f1a.x), "+v"(f1a.y), "+v"(f1a.z), "+v"(f1a.w),
        "+v"(f2a.x), "+v"(f2a.y), "+v"(f2a.z), "+v"(f2a.w),
        "+v"(f0b.x), "+v"(f0b.y), "+v"(f0b.z), "+v"(f0b.w),
        "+v"(f1b.x), "+v"(f1b.y), "+v"(f1b.z), "+v"(f1b.w),
        "+v"(f2b.x), "+v"(f2b.y), "+v"(f2b.z), "+v"(f2b.w));
    __syncthreads();

    const float SX = (float)WW / (float)(WW - 1);
    const float SY = (float)HH / (float)(HH - 1);
    const float SZ = (float)DD / (float)(DD - 1);

    unsigned oow = 0;   // 8-bit out-of-window mask

    // ---- hot loop: pure LDS, no global access ----
    #pragma unroll
    for (int g2 = 0; g2 < 2; ++g2) {
        int gz = gz0 + g2 * 4, gy = gy0;
        int idx = g2 ? idx1 : idx0;
        const float4 fz4 = g2 ? f0b : f0a;
        const float4 fy4 = g2 ? f1b : f1a;
        const float4 fx4 = g2 ? f2b : f2a;
        const float* pzf = (const float*)&fz4;
        const float* pyf = (const float*)&fy4;
        const float* pxf = (const float*)&fx4;

        float res[4];
        #pragma unroll
        for (int v = 0; v < 4; ++v) {
            float ux = fmaf((float)(gx + v) + pxf[v], SX, -0.5f);
            float uy = fmaf((float)gy + pyf[v],       SY, -0.5f);
            float uz = fmaf((float)gz + pzf[v],       SZ, -0.5f);
            ux = fminf(fmaxf(ux, 0.0f), (float)(WW - 1));
            uy = fminf(fmaxf(uy, 0.0f), (float)(HH - 1));
            uz = fminf(fmaxf(uz, 0.0f), (float)(DD - 1));
            float x0f = floorf(ux), y0f = floorf(uy), z0f = floorf(uz);
            float fx = ux - x0f, fy = uy - y0f, fz = uz - z0f;
            int lx0 = (int)x0f - xlo, ly0 = (int)y0f - ylo, lz0 = (int)z0f - zlo;
            bool in = ((unsigned)lz0 <= (unsigned)(WIN_Z - 2)) &
                      ((unsigned)ly0 <= (unsigned)(WIN_Y - 2)) &
                      ((unsigned)lx0 <= (unsigned)(WIN_X - 2));
            oow |= ((unsigned)!in) << (g2 * 4 + v);
            // clamped (safe) indices; OOW results are overwritten later
            int lx = min(max(lx0, 0), WIN_X - 2);
            int ly = min(max(ly0, 0), WIN_Y - 2);
            int lz = min(max(lz0, 0), WIN_Z - 2);

            int e = (lz * WIN_Y + ly) * WIN_X + lx;
            float c000 = bf2f(sbuf[e]);                 float c001 = bf2f(sbuf[e + 1]);
            float c010 = bf2f(sbuf[e + SROWY]);         float c011 = bf2f(sbuf[e + SROWY + 1]);
            float c100 = bf2f(sbuf[e + SROWZ]);         float c101 = bf2f(sbuf[e + SROWZ + 1]);
            float c110 = bf2f(sbuf[e + SROWZ + SROWY]); float c111 = bf2f(sbuf[e + SROWZ + SROWY + 1]);

            float r00 = fmaf(fx, c001 - c000, c000);
            float r01 = fmaf(fx, c011 - c010, c010);
            float r10 = fmaf(fx, c101 - c100, c100);
            float r11 = fmaf(fx, c111 - c110, c110);
            float r0  = fmaf(fy, r01 - r00, r00);
            float r1  = fmaf(fy, r11 - r10, r10);
            res[v]    = fmaf(fz, r1 - r0, r0);
        }
        *(float4*)(out + idx) = make_float4(res[0], res[1], res[2], res[3]);
    }

    // ---- OOW voxels: queue (overlaid on dead sbuf) + batched fix-up ----
    __syncthreads();                       // sbuf reads done; safe to overlay
    float4* queue = (float4*)sbuf;         // {idx, ux, uy, uz}; max 2048*16B fits

    if (oow) {
        #pragma unroll
        for (int g2 = 0; g2 < 2; ++g2) {
            int gz = gz0 + g2 * 4, gy = gy0;
            int idx = g2 ? idx1 : idx0;
            const float4 fz4 = g2 ? f0b : f0a;
            const float4 fy4 = g2 ? f1b : f1a;
            const float4 fx4 = g2 ? f2b : f2a;
            const float* pzf = (const float*)&fz4;
            const float* pyf = (const float*)&fy4;
            const float* pxf = (const float*)&fx4;
            #pragma unroll
            for (int v = 0; v < 4; ++v) {
                if (oow & (1u << (g2 * 4 + v))) {
                    float ux = fmaf((float)(gx + v) + pxf[v], SX, -0.5f);
                    float uy = fmaf((float)gy + pyf[v],       SY, -0.5f);
                    float uz = fmaf((float)gz + pzf[v],       SZ, -0.5f);
                    int pos = atomicAdd(&qcount, 1);
                    queue[pos] = make_float4(__int_as_float(idx + v), ux, uy, uz);
                }
            }
        }
    }
    __syncthreads();

    int nq = qcount;
    for (int i = tid; i < nq; i += 256) {
        float4 qe = queue[i];
        int oidx = __float_as_int(qe.x);
        float ux = fminf(fmaxf(qe.y, 0.0f), (float)(WW - 1));
        float uy = fminf(fmaxf(qe.z, 0.0f), (float)(HH - 1));
        float uz = fminf(fmaxf(qe.w, 0.0f), (float)(DD - 1));
        float x0f = floorf(ux), y0f = floorf(uy), z0f = floorf(uz);
        float fx = ux - x0f, fy = uy - y0f, fz = uz - z0f;
        int x0 = (int)x0f, y0 = (int)y0f, z0 = (int)z0f;
        int y1 = min(y0 + 1, HH - 1);
        int z1 = min(z0 + 1, DD - 1);
        int xb = min(x0, WW - 2);
        bool xe = (x0 == WW - 1);
        F2 q00 = *(const F2*)(src + ((size_t)z0 * HH + y0) * WW + xb);
        F2 q01 = *(const F2*)(src + ((size_t)z0 * HH + y1) * WW + xb);
        F2 q10 = *(const F2*)(src + ((size_t)z1 * HH + y0) * WW + xb);
        F2 q11 = *(const F2*)(src + ((size_t)z1 * HH + y1) * WW + xb);
        float c000 = xe ? q00.b : q00.a, c001 = q00.b;
        float c010 = xe ? q01.b : q01.a, c011 = q01.b;
        float c100 = xe ? q10.b : q10.a, c101 = q10.b;
        float c110 = xe ? q11.b : q11.a, c111 = q11.b;
        float r00 = fmaf(fx, c001 - c000, c000);
        float r01 = fmaf(fx, c011 - c010, c010);
        float r10 = fmaf(fx, c101 - c100, c100);
        float r11 = fmaf(fx, c111 - c110, c110);
        float r0  = fmaf(fy, r01 - r00, r00);
        float r1  = fmaf(fy, r11 - r10, r10);
        out[oidx] = fmaf(fz, r1 - r0, r0);
    }
}

extern "C" void kernel_launch(void* const* d_in, const int* in_sizes, int n_in,
                              void* d_out, int out_size, void* d_ws, size_t ws_size,
                              hipStream_t stream) {
    const float* src  = (const float*)d_in[0];   // [1,1,D,H,W]
    const float* flow = (const float*)d_in[1];   // [1,3,D,H,W]
    // d_in[2] identity grid: unused (recomputed); d_ws unused
    float* out = (float*)d_out;

    warp_tile_kernel<<<NTILES, 256, 0, stream>>>(src, flow, out);
}

// Round 10
// 176.627 us; speedup vs baseline: 1.1591x; 1.1591x over previous
//
#include <hip/hip_runtime.h>

// Spatial transformer: trilinear warp of src by flow, border padding.
// D=160, H=192, W=160.  u = (idx + flow) * S/(S-1) - 0.5, clamp, trilinear.
// grid input (identity meshgrid) recomputed from thread index.
//
// Lineage: R5 (4-parity bf16 stencil table, best known: 51us) with the two
// 8B gathers per voxel merged into ONE global_load_dwordx4 (asm; HW needs
// only dword alignment). R1->R2->R5 times track VMEM request count
// (8->4->2 req/voxel = 141->98->51us); this tests 2->1.

#define DD 160
#define HH 192
#define WW 160
#define DHW (DD * HH * WW)
#define ZP (DD / 2)   /* 80 */
#define YP (HH / 2)   /* 96 */
#define COPY_ENTRIES (ZP * YP * WW)            /* 1,228,800 entries x 8B */
#define WS_NEEDED (4ULL * COPY_ENTRIES * 8ULL) /* 39,321,600 B */

typedef unsigned int u32x4 __attribute__((ext_vector_type(4)));

__device__ __forceinline__ unsigned short bf16_rn(float f) {
    unsigned int u = __float_as_uint(f);
    return (unsigned short)((u + 0x7FFFu + ((u >> 16) & 1u)) >> 16);
}

// ---------------- prepass: build 4 parity-packed bf16 stencil copies ----------------
// copy(cz,cy) entry [zp][yp][x] (2 uints):
//   u0 = bf(z0,y0,x) | bf(z1,y0,x)<<16
//   u1 = bf(z0,y1,x) | bf(z1,y1,x)<<16
// where z0=2*zp+cz, z1=min(z0+1,DD-1), y0=2*yp+cy, y1=min(y0+1,HH-1).
__global__ __launch_bounds__(256) void pack_kernel(
    const float* __restrict__ src, unsigned int* __restrict__ tab)
{
    int t = blockIdx.x * 256 + (int)threadIdx.x;   // 307,200 threads
    int xq  = t % (WW / 4);
    int rem = t / (WW / 4);
    int yp  = rem % YP;
    int zp  = rem / YP;                             // [0,80)
    int x = xq * 4;

    int zs[3] = { 2 * zp, 2 * zp + 1, min(2 * zp + 2, DD - 1) };
    int ys[3] = { 2 * yp, 2 * yp + 1, min(2 * yp + 2, HH - 1) };

    float4 r[3][3];
    #pragma unroll
    for (int i = 0; i < 3; ++i)
        #pragma unroll
        for (int j = 0; j < 3; ++j)
            r[i][j] = *(const float4*)(src + ((size_t)zs[i] * HH + ys[j]) * WW + x);

    #pragma unroll
    for (int cz = 0; cz < 2; ++cz)
        #pragma unroll
        for (int cy = 0; cy < 2; ++cy) {
            unsigned int e[8];
            #pragma unroll
            for (int k = 0; k < 4; ++k) {
                float a = ((const float*)&r[cz    ][cy    ])[k];
                float b = ((const float*)&r[cz + 1][cy    ])[k];
                float c = ((const float*)&r[cz    ][cy + 1])[k];
                float d = ((const float*)&r[cz + 1][cy + 1])[k];
                e[2 * k]     = (unsigned int)bf16_rn(a) | ((unsigned int)bf16_rn(b) << 16);
                e[2 * k + 1] = (unsigned int)bf16_rn(c) | ((unsigned int)bf16_rn(d) << 16);
            }
            unsigned int* dst = tab +
                ((size_t)(cz * 2 + cy) * COPY_ENTRIES + ((size_t)zp * YP + yp) * WW + x) * 2;
            *(uint4*)(dst)     = make_uint4(e[0], e[1], e[2], e[3]);
            *(uint4*)(dst + 4) = make_uint4(e[4], e[5], e[6], e[7]);
        }
}

// ---------------- main: 1x 16B gather per voxel ----------------
__global__ __launch_bounds__(256) void warp_kernel(
    const unsigned int* __restrict__ tab,
    const float* __restrict__ flow,
    float* __restrict__ out)
{
    // XCD swizzle: XCD k gets contiguous blocks [600k,600k+600) -> its slab
    // of the table stays hot in L2/L3.
    int b = blockIdx.x;
    int nb = (b & 7) * 600 + (b >> 3);
    int base = (nb * 256 + (int)threadIdx.x) * 4;

    int w = base % WW;
    int tmp = base / WW;
    int h = tmp % HH;
    int d = tmp / HH;

    const float4 f0  = *(const float4*)(flow + base);           // -> D/z
    const float4 f1  = *(const float4*)(flow + DHW + base);     // -> H/y
    const float4 f2v = *(const float4*)(flow + 2 * DHW + base); // -> W/x
    const float* fl0 = (const float*)&f0;
    const float* fl1 = (const float*)&f1;
    const float* fl2 = (const float*)&f2v;

    const float SX = (float)WW / (float)(WW - 1);
    const float SY = (float)HH / (float)(HH - 1);
    const float SZ = (float)DD / (float)(DD - 1);

    float fx[4], fy[4], fz[4];
    bool  xe[4];
    const unsigned int* pp[4];

    // ---- phase 1: addresses & weights ----
    #pragma unroll
    for (int v = 0; v < 4; ++v) {
        float ux = fmaf((float)(w + v) + fl2[v], SX, -0.5f);
        float uy = fmaf((float)h + fl1[v],       SY, -0.5f);
        float uz = fmaf((float)d + fl0[v],       SZ, -0.5f);
        ux = fminf(fmaxf(ux, 0.0f), (float)(WW - 1));
        uy = fminf(fmaxf(uy, 0.0f), (float)(HH - 1));
        uz = fminf(fmaxf(uz, 0.0f), (float)(DD - 1));
        float x0f = floorf(ux), y0f = floorf(uy), z0f = floorf(uz);
        fx[v] = ux - x0f; fy[v] = uy - y0f; fz[v] = uz - z0f;
        int x0 = (int)x0f, y0 = (int)y0f, z0 = (int)z0f;
        int zp = z0 >> 1, cz = z0 & 1;
        int yp = y0 >> 1, cy = y0 & 1;
        int xb = min(x0, WW - 2);          // entries xb, xb+1
        xe[v] = (x0 == WW - 1);            // clamped: both x taps = entry xb+1
        pp[v] = tab + ((size_t)((cz << 1) | cy) * COPY_ENTRIES
                       + ((size_t)zp * YP + yp) * WW + xb) * 2;
    }

    // ---- phase 2: ONE dwordx4 per voxel (addr is 8B-aligned; HW needs 4B) ----
    u32x4 q[4];
    #pragma unroll
    for (int v = 0; v < 4; ++v)
        asm volatile("global_load_dwordx4 %0, %1, off"
                     : "=v"(q[v]) : "v"(pp[v]));
    asm volatile("s_waitcnt vmcnt(0)"
                 : "+v"(q[0]), "+v"(q[1]), "+v"(q[2]), "+v"(q[3])
                 :: "memory");

    // ---- phase 3: interpolate ----
    float res[4];
    #pragma unroll
    for (int v = 0; v < 4; ++v) {
        unsigned int lox = q[v].x;   // entry xb  : (z0,y0),(z1,y0)
        unsigned int loy = q[v].y;   //            (z0,y1),(z1,y1)
        unsigned int hix = q[v].z;   // entry xb+1
        unsigned int hiy = q[v].w;
        unsigned int a0 = xe[v] ? hix : lox;
        unsigned int a1 = xe[v] ? hiy : loy;

        float c000 = __uint_as_float(a0 << 16);
        float c100 = __uint_as_float(a0 & 0xFFFF0000u);
        float c010 = __uint_as_float(a1 << 16);
        float c110 = __uint_as_float(a1 & 0xFFFF0000u);
        float c001 = __uint_as_float(hix << 16);
        float c101 = __uint_as_float(hix & 0xFFFF0000u);
        float c011 = __uint_as_float(hiy << 16);
        float c111 = __uint_as_float(hiy & 0xFFFF0000u);

        float r00 = fmaf(fx[v], c001 - c000, c000);
        float r01 = fmaf(fx[v], c011 - c010, c010);
        float r10 = fmaf(fx[v], c101 - c100, c100);
        float r11 = fmaf(fx[v], c111 - c110, c110);
        float r0  = fmaf(fy[v], r01 - r00, r00);
        float r1  = fmaf(fy[v], r11 - r10, r10);
        res[v]    = fmaf(fz[v], r1 - r0, r0);
    }

    *(float4*)(out + base) = make_float4(res[0], res[1], res[2], res[3]);
}

// ---------------- fallback (proven R2 kernel) if ws too small ----------------
struct __align__(4) F2 { float a, b; };

__global__ __launch_bounds__(256) void warp_direct_kernel(
    const float* __restrict__ src,
    const float* __restrict__ flow,
    float* __restrict__ out)
{
    int b = blockIdx.x;
    int nb = (b & 7) * 600 + (b >> 3);
    int base = (nb * 256 + (int)threadIdx.x) * 4;

    int w = base % WW;
    int tmp = base / WW;
    int h = tmp % HH;
    int d = tmp / HH;

    const float4 f0  = *(const float4*)(flow + base);
    const float4 f1  = *(const float4*)(flow + DHW + base);
    const float4 f2v = *(const float4*)(flow + 2 * DHW + base);
    const float* f0p = (const float*)&f0;
    const float* f1p = (const float*)&f1;
    const float* f2p = (const float*)&f2v;

    const float SX = (float)WW / (float)(WW - 1);
    const float SY = (float)HH / (float)(HH - 1);
    const float SZ = (float)DD / (float)(DD - 1);

    float res[4];
    #pragma unroll
    for (int v = 0; v < 4; ++v) {
        float ux = fmaf((float)(w + v) + f2p[v], SX, -0.5f);
        float uy = fmaf((float)h + f1p[v],       SY, -0.5f);
        float uz = fmaf((float)d + f0p[v],       SZ, -0.5f);
        ux = fminf(fmaxf(ux, 0.0f), (float)(WW - 1));
        uy = fminf(fmaxf(uy, 0.0f), (float)(HH - 1));
        uz = fminf(fmaxf(uz, 0.0f), (float)(DD - 1));
        float x0f = floorf(ux), y0f = floorf(uy), z0f = floorf(uz);
        float fx = ux - x0f, fy = uy - y0f, fz = uz - z0f;
        int x0 = (int)x0f, y0 = (int)y0f, z0 = (int)z0f;
        int y1 = min(y0 + 1, HH - 1);
        int z1 = min(z0 + 1, DD - 1);
        int xb = min(x0, WW - 2);
        bool xe = (x0 == WW - 1);
        F2 q00 = *(const F2*)(src + ((size_t)z0 * HH + y0) * WW + xb);
        F2 q01 = *(const F2*)(src + ((size_t)z0 * HH + y1) * WW + xb);
        F2 q10 = *(const F2*)(src + ((size_t)z1 * HH + y0) * WW + xb);
        F2 q11 = *(const F2*)(src + ((size_t)z1 * HH + y1) * WW + xb);
        float c000 = xe ? q00.b : q00.a, c001 = q00.b;
        float c010 = xe ? q01.b : q01.a, c011 = q01.b;
        float c100 = xe ? q10.b : q10.a, c101 = q10.b;
        float c110 = xe ? q11.b : q11.a, c111 = q11.b;
        float r00 = fmaf(fx, c001 - c000, c000);
        float r01 = fmaf(fx, c011 - c010, c010);
        float r10 = fmaf(fx, c101 - c100, c100);
        float r11 = fmaf(fx, c111 - c110, c110);
        float r0  = fmaf(fy, r01 - r00, r00);
        float r1  = fmaf(fy, r11 - r10, r10);
        res[v]    = fmaf(fz, r1 - r0, r0);
    }
    *(float4*)(out + base) = make_float4(res[0], res[1], res[2], res[3]);
}

extern "C" void kernel_launch(void* const* d_in, const int* in_sizes, int n_in,
                              void* d_out, int out_size, void* d_ws, size_t ws_size,
                              hipStream_t stream) {
    const float* src  = (const float*)d_in[0];   // [1,1,D,H,W]
    const float* flow = (const float*)d_in[1];   // [1,3,D,H,W]
    // d_in[2] identity grid: unused (recomputed)
    float* out = (float*)d_out;

    if (ws_size >= WS_NEEDED) {
        unsigned int* tab = (unsigned int*)d_ws;
        pack_kernel<<<(ZP * YP * (WW / 4)) / 256, 256, 0, stream>>>(src, tab);
        warp_kernel<<<DHW / 4 / 256, 256, 0, stream>>>(tab, flow, out);
    } else {
        warp_direct_kernel<<<DHW / 4 / 256, 256, 0, stream>>>(src, flow, out);
    }
}